// Round 10
// baseline (845.255 us; speedup 1.0000x reference)
//
#include <hip/hip_runtime.h>
#include <math.h>

typedef __attribute__((ext_vector_type(8))) short bf16x8;
typedef __attribute__((ext_vector_type(4))) float f32x4;
typedef __attribute__((ext_vector_type(2))) _Float16 h2;

#define BSHIFT 7               // 128 nodes per bucket
#define CH 8192                // edges per block in bucket hist/scatter

__device__ inline unsigned short f32_to_bf16_bits(float f) {
    unsigned int u = __float_as_uint(f);
    unsigned int r = (u + 0x7fffu + ((u >> 16) & 1u)) >> 16;   // RNE
    return (unsigned short)r;
}
__device__ inline float bf16_bits_to_f32(unsigned short h) {
    return __uint_as_float(((unsigned int)h) << 16);
}
__device__ inline h2 u2h(unsigned u) { return __builtin_bit_cast(h2, u); }
__device__ inline unsigned h2u(h2 h) { return __builtin_bit_cast(unsigned, h); }

// single-instruction lane xor-swizzle add (BitMode: (xor<<10)|0x1F)
#define SWZ_ADD(t, imm) \
    t += __int_as_float(__builtin_amdgcn_ds_swizzle(__float_as_int(t), imm))

// fp16 pair dot with f32 accumulate (v_dot2_f32_f16)
__device__ inline float dot2acc(h2 a, h2 b, float c) {
#if defined(__has_builtin)
#if __has_builtin(__builtin_amdgcn_fdot2)
    return __builtin_amdgcn_fdot2(a, b, c, false);
#else
    return c + (float)a[0] * (float)b[0] + (float)a[1] * (float)b[1];
#endif
#else
    return c + (float)a[0] * (float)b[0] + (float)a[1] * (float)b[1];
#endif
}

// ================= 2-level bucket CSR build =================

__global__ __launch_bounds__(256) void bucket_hist(
    const int* __restrict__ dst, int* __restrict__ bcnt8, int E, int nb, int nbp)
{
    __shared__ int h[1024];
    for (int i = threadIdx.x; i < nb; i += 256) h[i] = 0;
    __syncthreads();
    int e0 = blockIdx.x * CH, e1 = min(e0 + CH, E);
    for (int e = e0 + (int)threadIdx.x; e < e1; e += 256)
        atomicAdd(&h[dst[e] >> BSHIFT], 1);
    __syncthreads();
    int* mycnt = bcnt8 + (blockIdx.x & 7) * nbp;
    for (int b = threadIdx.x; b < nb; b += 256) {
        int c = h[b];
        if (c) atomicAdd(&mycnt[b], c);
    }
}

__global__ void bucket_scan(const int* __restrict__ bcnt8, int* __restrict__ bbase,
                            int* __restrict__ bcur8, int* __restrict__ rowstart,
                            int nb, int nbp, int E, int N)
{
    __shared__ int sh[1024];
    int t = threadIdx.x;
    int g8[8];
    int tot = 0;
#pragma unroll
    for (int g = 0; g < 8; ++g) {
        int c = (t < nb) ? bcnt8[g * nbp + t] : 0;
        g8[g] = c; tot += c;
    }
    sh[t] = tot;
    __syncthreads();
    for (int d = 1; d < 1024; d <<= 1) {
        int a = (t >= d) ? sh[t - d] : 0;
        __syncthreads();
        sh[t] += a;
        __syncthreads();
    }
    int base = sh[t] - tot;   // exclusive
    if (t <= nb) bbase[t] = base;
    if (t < nb) {
        int run = base;
#pragma unroll
        for (int g = 0; g < 8; ++g) { bcur8[g * nbp + t] = run; run += g8[g]; }
    }
    if (t == 0) rowstart[N] = E;
}

__global__ __launch_bounds__(256) void bucket_scatter(
    const int* __restrict__ src, const int* __restrict__ dst,
    int* __restrict__ bcur8, unsigned* __restrict__ pairs, int E, int nb, int nbp)
{
    __shared__ int h[1024];
    for (int i = threadIdx.x; i < nb; i += 256) h[i] = 0;
    __syncthreads();
    int e0 = blockIdx.x * CH, e1 = min(e0 + CH, E);
    for (int e = e0 + (int)threadIdx.x; e < e1; e += 256)
        atomicAdd(&h[dst[e] >> BSHIFT], 1);
    __syncthreads();
    int* mycur = bcur8 + (blockIdx.x & 7) * nbp;
    for (int b = threadIdx.x; b < nb; b += 256) {
        int c = h[b];
        if (c) h[b] = atomicAdd(&mycur[b], c);
    }
    __syncthreads();
    for (int e = e0 + (int)threadIdx.x; e < e1; e += 256) {
        int d = dst[e];
        int pos = atomicAdd(&h[d >> BSHIFT], 1);
        pairs[pos] = ((unsigned)src[e] << BSHIFT) | (unsigned)(d & 127);
    }
}

__global__ __launch_bounds__(256) void bucket_finalize(
    const unsigned* __restrict__ pairs, const int* __restrict__ bbase,
    int* __restrict__ rowstart, int* __restrict__ csr_src, int N)
{
    __shared__ int h[128];
    __shared__ int sh[256];
    int b = blockIdx.x;
    int p0 = bbase[b], p1 = bbase[b + 1];
    int t = threadIdx.x;
    if (t < 128) h[t] = 0;
    __syncthreads();
    for (int e = p0 + t; e < p1; e += 256)
        atomicAdd(&h[pairs[e] & 127], 1);
    __syncthreads();
    int v = (t < 128) ? h[t] : 0;
    sh[t] = v;
    __syncthreads();
    for (int d = 1; d < 256; d <<= 1) {
        int a = (t >= d) ? sh[t - d] : 0;
        __syncthreads();
        sh[t] += a;
        __syncthreads();
    }
    if (t < 128) {
        int off = sh[t] - v;
        int node = (b << BSHIFT) + t;
        if (node < N) rowstart[node] = p0 + off;
        h[t] = p0 + off;
    }
    __syncthreads();
    for (int e = p0 + t; e < p1; e += 256) {
        unsigned pr = pairs[e];
        int pos = atomicAdd(&h[pr & 127], 1);
        csr_src[pos] = (int)(pr >> BSHIFT);
    }
}

// ================= degree-sorted node permutation =================
// counting sort by degree (clamped to 255): waves of agg then process
// nodes of near-equal degree -> no group-divergence inside a wave.

__global__ void deg_hist(const int* __restrict__ rowstart, int* __restrict__ dhist, int N) {
    int i = blockIdx.x * blockDim.x + threadIdx.x;
    if (i < N) atomicAdd(&dhist[min(rowstart[i + 1] - rowstart[i], 255)], 1);
}

__global__ void deg_scan(const int* __restrict__ dhist, int* __restrict__ dcur) {
    __shared__ int sh[256];
    int t = threadIdx.x;
    int v = dhist[t];
    sh[t] = v;
    __syncthreads();
    for (int d = 1; d < 256; d <<= 1) {
        int a = (t >= d) ? sh[t - d] : 0;
        __syncthreads();
        sh[t] += a;
        __syncthreads();
    }
    dcur[t] = sh[t] - v;   // exclusive base
}

__global__ void deg_scatter(const int* __restrict__ rowstart, int* __restrict__ dcur,
                            int* __restrict__ perm, int N) {
    int i = blockIdx.x * blockDim.x + threadIdx.x;
    if (i < N) {
        int d = min(rowstart[i + 1] - rowstart[i], 255);
        int r = atomicAdd(&dcur[d], 1);
        perm[r] = i;
    }
}

// ================= weight prepack =================

__global__ void prepack_kernel(const float* __restrict__ Wl, const float* __restrict__ Wr,
                               unsigned short* __restrict__ pWl, unsigned short* __restrict__ pWr,
                               int FIN, int FOUT) {
    int NT = FOUT >> 4, NK = FIN >> 5;
    int part = NT * NK * 512;
    int i = blockIdx.x * blockDim.x + threadIdx.x;
    int m = i / part;
    if (m >= 2) return;
    int ii = i - m * part;
    int j = ii & 7;
    int lane = (ii >> 3) & 63;
    int rest = ii >> 9;
    int ks = rest % NK;
    int t = rest / NK;
    int k = ks * 32 + (lane >> 4) * 8 + j;
    int c = t * 16 + (lane & 15);
    const float* W = m ? Wr : Wl;
    unsigned short* P = m ? pWr : pWl;
    float w = W[(size_t)k * FOUT + c];
    unsigned short hi = f32_to_bf16_bits(w);
    unsigned short lo = f32_to_bf16_bits(w - bf16_bits_to_f32(hi));
    P[ii] = hi;
    P[part + ii] = lo;
}

// ================= MFMA projection + att-dot epilogue =================
// xl AND xr written as fp16 (agg tables); dl/dr stay f32.

template<int FIN, int FOUT>
__global__ __launch_bounds__(256) void proj_mfma_kernel(
    const float* __restrict__ x,
    const unsigned short* __restrict__ pWl, const unsigned short* __restrict__ pWr,
    const float* __restrict__ att,
    _Float16* __restrict__ xlh, _Float16* __restrict__ xrh,
    float* __restrict__ dl, float* __restrict__ dr, int n)
{
    constexpr int NT = FOUT >> 4;
    constexpr int NK = FIN >> 5;
    constexpr int PART = NT * NK * 512;
    const int wave = threadIdx.x >> 6;
    const int lane = threadIdx.x & 63;
    const int row0 = blockIdx.x * 64 + wave * 16;
    int arow = row0 + (lane & 15);
    if (arow >= n) arow = n - 1;
    const int khalf = lane >> 4;

    f32x4 accl[NT], accr[NT];
#pragma unroll
    for (int t = 0; t < NT; ++t) {
        accl[t] = (f32x4){0.f, 0.f, 0.f, 0.f};
        accr[t] = (f32x4){0.f, 0.f, 0.f, 0.f};
    }

    const float* xrow = x + (size_t)arow * FIN + khalf * 8;
#pragma unroll
    for (int ks = 0; ks < NK; ++ks) {
        float4 a0 = *(const float4*)(xrow + ks * 32);
        float4 a1 = *(const float4*)(xrow + ks * 32 + 4);
        float av[8] = {a0.x, a0.y, a0.z, a0.w, a1.x, a1.y, a1.z, a1.w};
        bf16x8 ah, al;
#pragma unroll
        for (int j = 0; j < 8; ++j) {
            unsigned short h = f32_to_bf16_bits(av[j]);
            ah[j] = (short)h;
            al[j] = (short)f32_to_bf16_bits(av[j] - bf16_bits_to_f32(h));
        }
#pragma unroll
        for (int t = 0; t < NT; ++t) {
            const unsigned short* bpl = pWl + ((size_t)(t * NK + ks) * 64 + lane) * 8;
            bf16x8 bh  = *(const bf16x8*)bpl;
            bf16x8 blo = *(const bf16x8*)(bpl + PART);
            accl[t] = __builtin_amdgcn_mfma_f32_16x16x32_bf16(ah, bh,  accl[t], 0, 0, 0);
            accl[t] = __builtin_amdgcn_mfma_f32_16x16x32_bf16(ah, blo, accl[t], 0, 0, 0);
            accl[t] = __builtin_amdgcn_mfma_f32_16x16x32_bf16(al, bh,  accl[t], 0, 0, 0);
            const unsigned short* bpr = pWr + ((size_t)(t * NK + ks) * 64 + lane) * 8;
            bh  = *(const bf16x8*)bpr;
            blo = *(const bf16x8*)(bpr + PART);
            accr[t] = __builtin_amdgcn_mfma_f32_16x16x32_bf16(ah, bh,  accr[t], 0, 0, 0);
            accr[t] = __builtin_amdgcn_mfma_f32_16x16x32_bf16(ah, blo, accr[t], 0, 0, 0);
            accr[t] = __builtin_amdgcn_mfma_f32_16x16x32_bf16(al, bh,  accr[t], 0, 0, 0);
        }
    }

    const int orow0 = row0 + khalf * 4;
    const int colb = lane & 15;
    float attc[NT];
#pragma unroll
    for (int t = 0; t < NT; ++t) attc[t] = att[t * 16 + colb];

#pragma unroll
    for (int t = 0; t < NT; ++t) {
        int col = t * 16 + colb;
#pragma unroll
        for (int r = 0; r < 4; ++r) {
            int rr = orow0 + r;
            if (rr < n) {
                xlh[(size_t)rr * FOUT + col] = (_Float16)accl[t][r];
                xrh[(size_t)rr * FOUT + col] = (_Float16)accr[t][r];
            }
        }
    }
#pragma unroll
    for (int r = 0; r < 4; ++r) {
        float pl = 0.f, pr = 0.f;
#pragma unroll
        for (int t = 0; t < NT; ++t) { pl += accl[t][r] * attc[t]; pr += accr[t][r] * attc[t]; }
#pragma unroll
        for (int off = 1; off < 16; off <<= 1) {
            pl += __shfl_xor(pl, off);
            pr += __shfl_xor(pr, off);
        }
        int rr = orow0 + r;
        if (colb == 0 && rr < n) { dl[rr] = pl; dr[rr] = pr; }
    }
}

// ================= per-dst online-softmax aggregation =================
// Group-per-node via degree-sorted perm (uniform degree per wave),
// 8 feats/lane packed-fp16 math, 3-stage (distance-2) pipeline,
// pair-merged defer-max. score = 0.6*(dl+dr) + 0.4*sum(att*|s|).

template<int F, int AMODE>
__global__ __launch_bounds__(256) void agg_kernel(
    const _Float16* __restrict__ xlh, const _Float16* __restrict__ xrh,
    const float* __restrict__ att,
    const float* __restrict__ dl, const float* __restrict__ dr,
    const int* __restrict__ rowstart, const int* __restrict__ csr_src,
    const int* __restrict__ perm,
    float* __restrict__ out, int n, int E)
{
    constexpr int LPE = F / 8;            // lanes per node (8 feats/lane)
    constexpr int LSH = (F == 64) ? 6 : 5;
    constexpr int NPG = 64 / LPE;         // nodes per wave

    int wv  = (blockIdx.x * blockDim.x + threadIdx.x) >> 6;
    int lane = threadIdx.x & 63;
    int grp = lane / LPE;
    int fl  = lane % LPE;
    int idx = wv * NPG + grp;
    bool act = idx < n;
    int node = act ? perm[idx] : 0;

    float4 xrraw = *(const float4*)(xrh + (((unsigned)node << LSH) + fl * 8));
    h2 xrv[4];
#pragma unroll
    for (int j = 0; j < 4; ++j) xrv[j] = u2h(((const unsigned*)&xrraw)[j]);
    h2 atth[4];
#pragma unroll
    for (int j = 0; j < 4; ++j) {
        atth[j][0] = (_Float16)att[fl * 8 + 2 * j];
        atth[j][1] = (_Float16)att[fl * 8 + 2 * j + 1];
    }
    float cdr = 0.6f * dr[node];

    int s0 = rowstart[node];
    int s1 = act ? rowstart[node + 1] : s0;
    int s1c = min(max(s1 - 1, s0), E - 1);   // clamp inside own segment

    float m = -1e30f, mth = -1e30f, ssum = 0.f;
    float o[8];
#pragma unroll
    for (int j = 0; j < 8; ++j) o[j] = 0.f;

    // 3-stage pipeline: stage0 = edges (i0,i0+1), stage1 = (+2,+3), prefetch (+4,+5)
    int i0 = s0;
    int sa = csr_src[min(s0,     s1c)];
    int sb = csr_src[min(s0 + 1, s1c)];
    float da0 = dl[sa], db0 = dl[sb];
    float4 ra0 = *(const float4*)(xlh + (((unsigned)sa << LSH) + fl * 8));
    float4 rb0 = *(const float4*)(xlh + (((unsigned)sb << LSH) + fl * 8));
    sa = csr_src[min(s0 + 2, s1c)];
    sb = csr_src[min(s0 + 3, s1c)];
    float da1 = dl[sa], db1 = dl[sb];
    float4 ra1 = *(const float4*)(xlh + (((unsigned)sa << LSH) + fl * 8));
    float4 rb1 = *(const float4*)(xlh + (((unsigned)sb << LSH) + fl * 8));

    while (i0 < s1) {
        // prefetch stage2 (distance-2)
        int p2 = i0 + 4;
        int sa2 = csr_src[min(p2,     s1c)];
        int sb2 = csr_src[min(p2 + 1, s1c)];
        float da2 = dl[sa2], db2 = dl[sb2];
        float4 ra2 = *(const float4*)(xlh + (((unsigned)sa2 << LSH) + fl * 8));
        float4 rb2 = *(const float4*)(xlh + (((unsigned)sb2 << LSH) + fl * 8));

        h2 a[4], b[4];
#pragma unroll
        for (int j = 0; j < 4; ++j) {
            a[j] = u2h(((const unsigned*)&ra0)[j]);
            b[j] = u2h(((const unsigned*)&rb0)[j]);
        }

        bool vb = (i0 + 1) < s1;
        float ta = 0.f, tb = 0.f;
#pragma unroll
        for (int j = 0; j < 4; ++j) {
            h2 ea = a[j] + xrv[j];                       // v_pk_add_f16
            h2 eb = b[j] + xrv[j];
            ea = u2h(h2u(ea) & 0x7FFF7FFFu);             // packed |.|
            eb = u2h(h2u(eb) & 0x7FFF7FFFu);
            ta = dot2acc(atth[j], ea, ta);               // v_dot2_f32_f16
            tb = dot2acc(atth[j], eb, tb);
        }
        SWZ_ADD(ta, 0x041F); SWZ_ADD(tb, 0x041F);        // xor 1
        SWZ_ADD(ta, 0x081F); SWZ_ADD(tb, 0x081F);        // xor 2
        if (LPE == 8) { SWZ_ADD(ta, 0x101F); SWZ_ADD(tb, 0x101F); }  // xor 4

        float pa = 0.6f * da0 + cdr + 0.4f * ta;
        float pb = vb ? (0.6f * db0 + cdr + 0.4f * tb) : -1e30f;

        float pm = fmaxf(pa, pb);
        if (pm > mth) {                   // rare after first pair
            float c = __expf(m - pm);
            ssum *= c;
#pragma unroll
            for (int j = 0; j < 8; ++j) o[j] *= c;
            m = pm; mth = pm + 8.0f;
        }
        float wa = __expf(pa - m);
        float wb = __expf(pb - m);        // 0 when masked
        ssum += wa + wb;
#pragma unroll
        for (int j = 0; j < 4; ++j) {
            o[2 * j]     += wa * (float)a[j][0] + wb * (float)b[j][0];
            o[2 * j + 1] += wa * (float)a[j][1] + wb * (float)b[j][1];
        }

        i0 += 2;
        da0 = da1; db0 = db1; ra0 = ra1; rb0 = rb1;
        da1 = da2; db1 = db2; ra1 = ra2; rb1 = rb2;
    }

    float inv = 1.f / (ssum + 1e-16f);
    float res[8];
#pragma unroll
    for (int j = 0; j < 8; ++j) {
        float r = o[j] * inv;
        if (AMODE == 1) r = (r > 0.f) ? r : expm1f(r);
        else            r = (r > 0.f) ? r : 32.f * expm1f(r);
        res[j] = r;
    }
    if (act) {
        float* op = out + (((unsigned)node << LSH) + fl * 8);
        *(float4*)op       = (float4){res[0], res[1], res[2], res[3]};
        *(float4*)(op + 4) = (float4){res[4], res[5], res[6], res[7]};
    }
}

// ================= launcher =================

extern "C" void kernel_launch(void* const* d_in, const int* in_sizes, int n_in,
                              void* d_out, int out_size, void* d_ws, size_t ws_size,
                              hipStream_t stream) {
    const float* x    = (const float*)d_in[0];
    const int*   ei   = (const int*)d_in[1];
    const float* Wl1  = (const float*)d_in[2];
    const float* Wr1  = (const float*)d_in[3];
    const float* att1 = (const float*)d_in[4];
    const float* Wl2  = (const float*)d_in[5];
    const float* Wr2  = (const float*)d_in[6];
    const float* att2 = (const float*)d_in[7];
    const float* Wl3  = (const float*)d_in[8];
    const float* Wr3  = (const float*)d_in[9];
    const float* att3 = (const float*)d_in[10];
    const float* Wl4  = (const float*)d_in[11];
    const float* Wr4  = (const float*)d_in[12];
    const float* att4 = (const float*)d_in[13];

    const int N = in_sizes[0] / 128;
    const int E = in_sizes[1] / 2;
    const int* src = ei;
    const int* dst = ei + E;

    const int nb  = (N + 127) >> BSHIFT;
    const int nbp = (nb + 15) & ~15;

    char* w = (char*)d_ws;
    size_t off = 0;
    auto take = [&](size_t bytes) -> void* {
        void* p = w + off;
        off = (off + bytes + 255) & ~(size_t)255;
        return p;
    };
    int* bcnt8    = (int*)take((size_t)8 * nbp * 4);
    int* bcur8    = (int*)take((size_t)8 * nbp * 4);
    int* bbase    = (int*)take((size_t)(nb + 1) * 4);
    int* rowstart = (int*)take((size_t)(N + 1) * 4);
    int* csr_src  = (int*)take((size_t)E * 4);
    int* dhist    = (int*)take(256 * 4);
    int* dcur     = (int*)take(256 * 4);
    int* perm     = (int*)take((size_t)N * 4);
    float* dl = (float*)take((size_t)N * 4);
    float* dr = (float*)take((size_t)N * 4);
    _Float16* xlh = (_Float16*)take((size_t)N * 64 * 2);
    _Float16* xrh = (_Float16*)take((size_t)N * 64 * 2);
    float* hA = (float*)take((size_t)N * 64 * 4);
    float* hB = (float*)take((size_t)N * 64 * 4);
    unsigned short* pWl1 = (unsigned short*)take(2 * 4 * 4 * 512 * 2);
    unsigned short* pWr1 = (unsigned short*)take(2 * 4 * 4 * 512 * 2);
    unsigned short* pWl2 = (unsigned short*)take(2 * 4 * 2 * 512 * 2);
    unsigned short* pWr2 = (unsigned short*)take(2 * 4 * 2 * 512 * 2);
    unsigned short* pWl3 = (unsigned short*)take(2 * 4 * 2 * 512 * 2);
    unsigned short* pWr3 = (unsigned short*)take(2 * 4 * 2 * 512 * 2);
    unsigned short* pWl4 = (unsigned short*)take(2 * 2 * 2 * 512 * 2);
    unsigned short* pWr4 = (unsigned short*)take(2 * 2 * 2 * 512 * 2);
    unsigned* pairs = (unsigned*)hA;   // aliases hA; consumed before layer-1 agg writes hA
    float* outf = (float*)d_out;

    hipMemsetAsync(bcnt8, 0, (size_t)8 * nbp * 4, stream);
    hipMemsetAsync(dhist, 0, 256 * 4, stream);

    prepack_kernel<<<(2 * 4 * 4 * 512 + 255) / 256, 256, 0, stream>>>(Wl1, Wr1, pWl1, pWr1, 128, 64);
    prepack_kernel<<<(2 * 4 * 2 * 512 + 255) / 256, 256, 0, stream>>>(Wl2, Wr2, pWl2, pWr2, 64, 64);
    prepack_kernel<<<(2 * 4 * 2 * 512 + 255) / 256, 256, 0, stream>>>(Wl3, Wr3, pWl3, pWr3, 64, 64);
    prepack_kernel<<<(2 * 2 * 2 * 512 + 255) / 256, 256, 0, stream>>>(Wl4, Wr4, pWl4, pWr4, 64, 32);

    int kgrid = (E + CH - 1) / CH;
    bucket_hist<<<kgrid, 256, 0, stream>>>(dst, bcnt8, E, nb, nbp);
    bucket_scan<<<1, 1024, 0, stream>>>(bcnt8, bbase, bcur8, rowstart, nb, nbp, E, N);
    bucket_scatter<<<kgrid, 256, 0, stream>>>(src, dst, bcur8, pairs, E, nb, nbp);
    bucket_finalize<<<nb, 256, 0, stream>>>(pairs, bbase, rowstart, csr_src, N);

    // degree-sorted permutation (graph is layer-invariant)
    int ngrid = (N + 255) / 256;
    deg_hist<<<ngrid, 256, 0, stream>>>(rowstart, dhist, N);
    deg_scan<<<1, 256, 0, stream>>>(dhist, dcur);
    deg_scatter<<<ngrid, 256, 0, stream>>>(rowstart, dcur, perm, N);

    int pblk = (N + 63) / 64;
    int agg64 = (N + 31) / 32;    // 4 waves/block, 8 nodes/wave
    int agg32 = (N + 63) / 64;    // 4 waves/block, 16 nodes/wave

    // layer 1: 128 -> 64, ELU
    proj_mfma_kernel<128, 64><<<pblk, 256, 0, stream>>>(x, pWl1, pWr1, att1, xlh, xrh, dl, dr, N);
    agg_kernel<64, 1><<<agg64, 256, 0, stream>>>(xlh, xrh, att1, dl, dr, rowstart, csr_src, perm, hA, N, E);

    // layer 2: 64 -> 64, ELU
    proj_mfma_kernel<64, 64><<<pblk, 256, 0, stream>>>(hA, pWl2, pWr2, att2, xlh, xrh, dl, dr, N);
    agg_kernel<64, 1><<<agg64, 256, 0, stream>>>(xlh, xrh, att2, dl, dr, rowstart, csr_src, perm, hB, N, E);

    // layer 3: 64 -> 64, ELU
    proj_mfma_kernel<64, 64><<<pblk, 256, 0, stream>>>(hB, pWl3, pWr3, att3, xlh, xrh, dl, dr, N);
    agg_kernel<64, 1><<<agg64, 256, 0, stream>>>(xlh, xrh, att3, dl, dr, rowstart, csr_src, perm, hA, N, E);

    // layer 4: 64 -> 32, final ELU (alpha = 32)
    proj_mfma_kernel<64, 32><<<pblk, 256, 0, stream>>>(hA, pWl4, pWr4, att4, xlh, xrh, dl, dr, N);
    agg_kernel<32, 2><<<agg32, 256, 0, stream>>>(xlh, xrh, att4, dl, dr, rowstart, csr_src, perm, outf, N, E);
}

// Round 11
// 334.089 us; speedup vs baseline: 2.5300x; 2.5300x over previous
//
#include <hip/hip_runtime.h>
#include <math.h>

typedef __attribute__((ext_vector_type(8))) short bf16x8;
typedef __attribute__((ext_vector_type(4))) float f32x4;
typedef __attribute__((ext_vector_type(2))) _Float16 h2;

#define BSHIFT 7               // 128 nodes per bucket
#define CH 8192                // edges per block in bucket hist/scatter
#define DCH 4096               // nodes per block in degree sort

__device__ inline unsigned short f32_to_bf16_bits(float f) {
    unsigned int u = __float_as_uint(f);
    unsigned int r = (u + 0x7fffu + ((u >> 16) & 1u)) >> 16;   // RNE
    return (unsigned short)r;
}
__device__ inline float bf16_bits_to_f32(unsigned short h) {
    return __uint_as_float(((unsigned int)h) << 16);
}
__device__ inline h2 u2h(unsigned u) { return __builtin_bit_cast(h2, u); }
__device__ inline unsigned h2u(h2 h) { return __builtin_bit_cast(unsigned, h); }

// single-instruction lane xor-swizzle add (BitMode: (xor<<10)|0x1F)
#define SWZ_ADD(t, imm) \
    t += __int_as_float(__builtin_amdgcn_ds_swizzle(__float_as_int(t), imm))

// fp16 pair dot with f32 accumulate (v_dot2_f32_f16)
__device__ inline float dot2acc(h2 a, h2 b, float c) {
#if defined(__has_builtin)
#if __has_builtin(__builtin_amdgcn_fdot2)
    return __builtin_amdgcn_fdot2(a, b, c, false);
#else
    return c + (float)a[0] * (float)b[0] + (float)a[1] * (float)b[1];
#endif
#else
    return c + (float)a[0] * (float)b[0] + (float)a[1] * (float)b[1];
#endif
}

// ================= 2-level bucket CSR build =================

__global__ __launch_bounds__(256) void bucket_hist(
    const int* __restrict__ dst, int* __restrict__ bcnt8, int E, int nb, int nbp)
{
    __shared__ int h[1024];
    for (int i = threadIdx.x; i < nb; i += 256) h[i] = 0;
    __syncthreads();
    int e0 = blockIdx.x * CH, e1 = min(e0 + CH, E);
    for (int e = e0 + (int)threadIdx.x; e < e1; e += 256)
        atomicAdd(&h[dst[e] >> BSHIFT], 1);
    __syncthreads();
    int* mycnt = bcnt8 + (blockIdx.x & 7) * nbp;
    for (int b = threadIdx.x; b < nb; b += 256) {
        int c = h[b];
        if (c) atomicAdd(&mycnt[b], c);
    }
}

__global__ void bucket_scan(const int* __restrict__ bcnt8, int* __restrict__ bbase,
                            int* __restrict__ bcur8, int* __restrict__ rowstart,
                            int nb, int nbp, int E, int N)
{
    __shared__ int sh[1024];
    int t = threadIdx.x;
    int g8[8];
    int tot = 0;
#pragma unroll
    for (int g = 0; g < 8; ++g) {
        int c = (t < nb) ? bcnt8[g * nbp + t] : 0;
        g8[g] = c; tot += c;
    }
    sh[t] = tot;
    __syncthreads();
    for (int d = 1; d < 1024; d <<= 1) {
        int a = (t >= d) ? sh[t - d] : 0;
        __syncthreads();
        sh[t] += a;
        __syncthreads();
    }
    int base = sh[t] - tot;   // exclusive
    if (t <= nb) bbase[t] = base;
    if (t < nb) {
        int run = base;
#pragma unroll
        for (int g = 0; g < 8; ++g) { bcur8[g * nbp + t] = run; run += g8[g]; }
    }
    if (t == 0) rowstart[N] = E;
}

__global__ __launch_bounds__(256) void bucket_scatter(
    const int* __restrict__ src, const int* __restrict__ dst,
    int* __restrict__ bcur8, unsigned* __restrict__ pairs, int E, int nb, int nbp)
{
    __shared__ int h[1024];
    for (int i = threadIdx.x; i < nb; i += 256) h[i] = 0;
    __syncthreads();
    int e0 = blockIdx.x * CH, e1 = min(e0 + CH, E);
    for (int e = e0 + (int)threadIdx.x; e < e1; e += 256)
        atomicAdd(&h[dst[e] >> BSHIFT], 1);
    __syncthreads();
    int* mycur = bcur8 + (blockIdx.x & 7) * nbp;
    for (int b = threadIdx.x; b < nb; b += 256) {
        int c = h[b];
        if (c) h[b] = atomicAdd(&mycur[b], c);
    }
    __syncthreads();
    for (int e = e0 + (int)threadIdx.x; e < e1; e += 256) {
        int d = dst[e];
        int pos = atomicAdd(&h[d >> BSHIFT], 1);
        pairs[pos] = ((unsigned)src[e] << BSHIFT) | (unsigned)(d & 127);
    }
}

__global__ __launch_bounds__(256) void bucket_finalize(
    const unsigned* __restrict__ pairs, const int* __restrict__ bbase,
    int* __restrict__ rowstart, int* __restrict__ csr_src, int N)
{
    __shared__ int h[128];
    __shared__ int sh[256];
    int b = blockIdx.x;
    int p0 = bbase[b], p1 = bbase[b + 1];
    int t = threadIdx.x;
    if (t < 128) h[t] = 0;
    __syncthreads();
    for (int e = p0 + t; e < p1; e += 256)
        atomicAdd(&h[pairs[e] & 127], 1);
    __syncthreads();
    int v = (t < 128) ? h[t] : 0;
    sh[t] = v;
    __syncthreads();
    for (int d = 1; d < 256; d <<= 1) {
        int a = (t >= d) ? sh[t - d] : 0;
        __syncthreads();
        sh[t] += a;
        __syncthreads();
    }
    if (t < 128) {
        int off = sh[t] - v;
        int node = (b << BSHIFT) + t;
        if (node < N) rowstart[node] = p0 + off;
        h[t] = p0 + off;
    }
    __syncthreads();
    for (int e = p0 + t; e < p1; e += 256) {
        unsigned pr = pairs[e];
        int pos = atomicAdd(&h[pr & 127], 1);
        csr_src[pos] = (int)(pr >> BSHIFT);
    }
}

// ================= degree-sorted node permutation =================
// hierarchical counting sort (no global atomics): per-block LDS hist ->
// one-block scan of the 256 x NBd matrix -> scatter with LDS cursors.

__global__ __launch_bounds__(256) void dsort_hist(
    const int* __restrict__ rowstart, int* __restrict__ bh, int N, int NBd)
{
    __shared__ int h[256];
    int t = threadIdx.x;
    h[t] = 0;
    __syncthreads();
    int n0 = blockIdx.x * DCH, n1 = min(n0 + DCH, N);
    for (int i = n0 + t; i < n1; i += 256)
        atomicAdd(&h[min(rowstart[i + 1] - rowstart[i], 255)], 1);
    __syncthreads();
    bh[t * NBd + blockIdx.x] = h[t];
}

__global__ void dsort_scan(int* __restrict__ bh, int NBd)
{
    __shared__ int sh[256];
    int t = threadIdx.x;
    int run = 0;
    for (int b = 0; b < NBd; ++b) {       // per-bin prefix over blocks
        int v = bh[t * NBd + b];
        bh[t * NBd + b] = run;
        run += v;
    }
    sh[t] = run;
    __syncthreads();
    for (int d = 1; d < 256; d <<= 1) {   // scan across bins
        int a = (t >= d) ? sh[t - d] : 0;
        __syncthreads();
        sh[t] += a;
        __syncthreads();
    }
    int base = sh[t] - run;               // exclusive bin base
    for (int b = 0; b < NBd; ++b) bh[t * NBd + b] += base;
}

__global__ __launch_bounds__(256) void dsort_scatter(
    const int* __restrict__ rowstart, const int* __restrict__ bh,
    int* __restrict__ perm, int N, int NBd)
{
    __shared__ int cur[256];
    int t = threadIdx.x;
    cur[t] = bh[t * NBd + blockIdx.x];
    __syncthreads();
    int n0 = blockIdx.x * DCH, n1 = min(n0 + DCH, N);
    for (int i = n0 + t; i < n1; i += 256) {
        int d = min(rowstart[i + 1] - rowstart[i], 255);
        int pos = atomicAdd(&cur[d], 1);  // LDS atomic: cheap
        perm[pos] = i;
    }
}

// ================= weight prepack =================

__global__ void prepack_kernel(const float* __restrict__ Wl, const float* __restrict__ Wr,
                               unsigned short* __restrict__ pWl, unsigned short* __restrict__ pWr,
                               int FIN, int FOUT) {
    int NT = FOUT >> 4, NK = FIN >> 5;
    int part = NT * NK * 512;
    int i = blockIdx.x * blockDim.x + threadIdx.x;
    int m = i / part;
    if (m >= 2) return;
    int ii = i - m * part;
    int j = ii & 7;
    int lane = (ii >> 3) & 63;
    int rest = ii >> 9;
    int ks = rest % NK;
    int t = rest / NK;
    int k = ks * 32 + (lane >> 4) * 8 + j;
    int c = t * 16 + (lane & 15);
    const float* W = m ? Wr : Wl;
    unsigned short* P = m ? pWr : pWl;
    float w = W[(size_t)k * FOUT + c];
    unsigned short hi = f32_to_bf16_bits(w);
    unsigned short lo = f32_to_bf16_bits(w - bf16_bits_to_f32(hi));
    P[ii] = hi;
    P[part + ii] = lo;
}

// ================= MFMA projection + att-dot epilogue =================

template<int FIN, int FOUT>
__global__ __launch_bounds__(256) void proj_mfma_kernel(
    const float* __restrict__ x,
    const unsigned short* __restrict__ pWl, const unsigned short* __restrict__ pWr,
    const float* __restrict__ att,
    _Float16* __restrict__ xlh, _Float16* __restrict__ xrh,
    float* __restrict__ dl, float* __restrict__ dr, int n)
{
    constexpr int NT = FOUT >> 4;
    constexpr int NK = FIN >> 5;
    constexpr int PART = NT * NK * 512;
    const int wave = threadIdx.x >> 6;
    const int lane = threadIdx.x & 63;
    const int row0 = blockIdx.x * 64 + wave * 16;
    int arow = row0 + (lane & 15);
    if (arow >= n) arow = n - 1;
    const int khalf = lane >> 4;

    f32x4 accl[NT], accr[NT];
#pragma unroll
    for (int t = 0; t < NT; ++t) {
        accl[t] = (f32x4){0.f, 0.f, 0.f, 0.f};
        accr[t] = (f32x4){0.f, 0.f, 0.f, 0.f};
    }

    const float* xrow = x + (size_t)arow * FIN + khalf * 8;
#pragma unroll
    for (int ks = 0; ks < NK; ++ks) {
        float4 a0 = *(const float4*)(xrow + ks * 32);
        float4 a1 = *(const float4*)(xrow + ks * 32 + 4);
        float av[8] = {a0.x, a0.y, a0.z, a0.w, a1.x, a1.y, a1.z, a1.w};
        bf16x8 ah, al;
#pragma unroll
        for (int j = 0; j < 8; ++j) {
            unsigned short h = f32_to_bf16_bits(av[j]);
            ah[j] = (short)h;
            al[j] = (short)f32_to_bf16_bits(av[j] - bf16_bits_to_f32(h));
        }
#pragma unroll
        for (int t = 0; t < NT; ++t) {
            const unsigned short* bpl = pWl + ((size_t)(t * NK + ks) * 64 + lane) * 8;
            bf16x8 bh  = *(const bf16x8*)bpl;
            bf16x8 blo = *(const bf16x8*)(bpl + PART);
            accl[t] = __builtin_amdgcn_mfma_f32_16x16x32_bf16(ah, bh,  accl[t], 0, 0, 0);
            accl[t] = __builtin_amdgcn_mfma_f32_16x16x32_bf16(ah, blo, accl[t], 0, 0, 0);
            accl[t] = __builtin_amdgcn_mfma_f32_16x16x32_bf16(al, bh,  accl[t], 0, 0, 0);
            const unsigned short* bpr = pWr + ((size_t)(t * NK + ks) * 64 + lane) * 8;
            bh  = *(const bf16x8*)bpr;
            blo = *(const bf16x8*)(bpr + PART);
            accr[t] = __builtin_amdgcn_mfma_f32_16x16x32_bf16(ah, bh,  accr[t], 0, 0, 0);
            accr[t] = __builtin_amdgcn_mfma_f32_16x16x32_bf16(ah, blo, accr[t], 0, 0, 0);
            accr[t] = __builtin_amdgcn_mfma_f32_16x16x32_bf16(al, bh,  accr[t], 0, 0, 0);
        }
    }

    const int orow0 = row0 + khalf * 4;
    const int colb = lane & 15;
    float attc[NT];
#pragma unroll
    for (int t = 0; t < NT; ++t) attc[t] = att[t * 16 + colb];

#pragma unroll
    for (int t = 0; t < NT; ++t) {
        int col = t * 16 + colb;
#pragma unroll
        for (int r = 0; r < 4; ++r) {
            int rr = orow0 + r;
            if (rr < n) {
                xlh[(size_t)rr * FOUT + col] = (_Float16)accl[t][r];
                xrh[(size_t)rr * FOUT + col] = (_Float16)accr[t][r];
            }
        }
    }
#pragma unroll
    for (int r = 0; r < 4; ++r) {
        float pl = 0.f, pr = 0.f;
#pragma unroll
        for (int t = 0; t < NT; ++t) { pl += accl[t][r] * attc[t]; pr += accr[t][r] * attc[t]; }
#pragma unroll
        for (int off = 1; off < 16; off <<= 1) {
            pl += __shfl_xor(pl, off);
            pr += __shfl_xor(pr, off);
        }
        int rr = orow0 + r;
        if (colb == 0 && rr < n) { dl[rr] = pl; dr[rr] = pr; }
    }
}

// ================= per-dst online-softmax aggregation =================
// Group-per-node via degree-sorted perm (uniform degree per wave),
// 8 feats/lane packed-fp16 math, 3-stage (distance-2) pipeline,
// pair-merged defer-max. score = 0.6*(dl+dr) + 0.4*sum(att*|s|).

template<int F, int AMODE>
__global__ __launch_bounds__(256) void agg_kernel(
    const _Float16* __restrict__ xlh, const _Float16* __restrict__ xrh,
    const float* __restrict__ att,
    const float* __restrict__ dl, const float* __restrict__ dr,
    const int* __restrict__ rowstart, const int* __restrict__ csr_src,
    const int* __restrict__ perm,
    float* __restrict__ out, int n, int E)
{
    constexpr int LPE = F / 8;            // lanes per node (8 feats/lane)
    constexpr int LSH = (F == 64) ? 6 : 5;
    constexpr int NPG = 64 / LPE;         // nodes per wave

    int wv  = (blockIdx.x * blockDim.x + threadIdx.x) >> 6;
    int lane = threadIdx.x & 63;
    int grp = lane / LPE;
    int fl  = lane % LPE;
    int idx = wv * NPG + grp;
    bool act = idx < n;
    int node = act ? perm[idx] : 0;

    float4 xrraw = *(const float4*)(xrh + (((unsigned)node << LSH) + fl * 8));
    h2 xrv[4];
#pragma unroll
    for (int j = 0; j < 4; ++j) xrv[j] = u2h(((const unsigned*)&xrraw)[j]);
    h2 atth[4];
#pragma unroll
    for (int j = 0; j < 4; ++j) {
        atth[j][0] = (_Float16)att[fl * 8 + 2 * j];
        atth[j][1] = (_Float16)att[fl * 8 + 2 * j + 1];
    }
    float cdr = 0.6f * dr[node];

    int s0 = rowstart[node];
    int s1 = act ? rowstart[node + 1] : s0;
    int s1c = min(max(s1 - 1, s0), E - 1);   // clamp inside own segment

    float m = -1e30f, mth = -1e30f, ssum = 0.f;
    float o[8];
#pragma unroll
    for (int j = 0; j < 8; ++j) o[j] = 0.f;

    // 3-stage pipeline: stage0 = edges (i0,i0+1), stage1 = (+2,+3), prefetch (+4,+5)
    int i0 = s0;
    int sa = csr_src[min(s0,     s1c)];
    int sb = csr_src[min(s0 + 1, s1c)];
    float da0 = dl[sa], db0 = dl[sb];
    float4 ra0 = *(const float4*)(xlh + (((unsigned)sa << LSH) + fl * 8));
    float4 rb0 = *(const float4*)(xlh + (((unsigned)sb << LSH) + fl * 8));
    sa = csr_src[min(s0 + 2, s1c)];
    sb = csr_src[min(s0 + 3, s1c)];
    float da1 = dl[sa], db1 = dl[sb];
    float4 ra1 = *(const float4*)(xlh + (((unsigned)sa << LSH) + fl * 8));
    float4 rb1 = *(const float4*)(xlh + (((unsigned)sb << LSH) + fl * 8));

    while (i0 < s1) {
        // prefetch stage2 (distance-2)
        int p2 = i0 + 4;
        int sa2 = csr_src[min(p2,     s1c)];
        int sb2 = csr_src[min(p2 + 1, s1c)];
        float da2 = dl[sa2], db2 = dl[sb2];
        float4 ra2 = *(const float4*)(xlh + (((unsigned)sa2 << LSH) + fl * 8));
        float4 rb2 = *(const float4*)(xlh + (((unsigned)sb2 << LSH) + fl * 8));

        h2 a[4], b[4];
#pragma unroll
        for (int j = 0; j < 4; ++j) {
            a[j] = u2h(((const unsigned*)&ra0)[j]);
            b[j] = u2h(((const unsigned*)&rb0)[j]);
        }

        bool vb = (i0 + 1) < s1;
        float ta = 0.f, tb = 0.f;
#pragma unroll
        for (int j = 0; j < 4; ++j) {
            h2 ea = a[j] + xrv[j];                       // v_pk_add_f16
            h2 eb = b[j] + xrv[j];
            ea = u2h(h2u(ea) & 0x7FFF7FFFu);             // packed |.|
            eb = u2h(h2u(eb) & 0x7FFF7FFFu);
            ta = dot2acc(atth[j], ea, ta);               // v_dot2_f32_f16
            tb = dot2acc(atth[j], eb, tb);
        }
        SWZ_ADD(ta, 0x041F); SWZ_ADD(tb, 0x041F);        // xor 1
        SWZ_ADD(ta, 0x081F); SWZ_ADD(tb, 0x081F);        // xor 2
        if (LPE == 8) { SWZ_ADD(ta, 0x101F); SWZ_ADD(tb, 0x101F); }  // xor 4

        float pa = 0.6f * da0 + cdr + 0.4f * ta;
        float pb = vb ? (0.6f * db0 + cdr + 0.4f * tb) : -1e30f;

        float pm = fmaxf(pa, pb);
        if (pm > mth) {                   // rare after first pair
            float c = __expf(m - pm);
            ssum *= c;
#pragma unroll
            for (int j = 0; j < 8; ++j) o[j] *= c;
            m = pm; mth = pm + 8.0f;
        }
        float wa = __expf(pa - m);
        float wb = __expf(pb - m);        // 0 when masked
        ssum += wa + wb;
#pragma unroll
        for (int j = 0; j < 4; ++j) {
            o[2 * j]     += wa * (float)a[j][0] + wb * (float)b[j][0];
            o[2 * j + 1] += wa * (float)a[j][1] + wb * (float)b[j][1];
        }

        i0 += 2;
        da0 = da1; db0 = db1; ra0 = ra1; rb0 = rb1;
        da1 = da2; db1 = db2; ra1 = ra2; rb1 = rb2;
    }

    float inv = 1.f / (ssum + 1e-16f);
    float res[8];
#pragma unroll
    for (int j = 0; j < 8; ++j) {
        float r = o[j] * inv;
        if (AMODE == 1) r = (r > 0.f) ? r : expm1f(r);
        else            r = (r > 0.f) ? r : 32.f * expm1f(r);
        res[j] = r;
    }
    if (act) {
        float* op = out + (((unsigned)node << LSH) + fl * 8);
        *(float4*)op       = (float4){res[0], res[1], res[2], res[3]};
        *(float4*)(op + 4) = (float4){res[4], res[5], res[6], res[7]};
    }
}

// ================= launcher =================

extern "C" void kernel_launch(void* const* d_in, const int* in_sizes, int n_in,
                              void* d_out, int out_size, void* d_ws, size_t ws_size,
                              hipStream_t stream) {
    const float* x    = (const float*)d_in[0];
    const int*   ei   = (const int*)d_in[1];
    const float* Wl1  = (const float*)d_in[2];
    const float* Wr1  = (const float*)d_in[3];
    const float* att1 = (const float*)d_in[4];
    const float* Wl2  = (const float*)d_in[5];
    const float* Wr2  = (const float*)d_in[6];
    const float* att2 = (const float*)d_in[7];
    const float* Wl3  = (const float*)d_in[8];
    const float* Wr3  = (const float*)d_in[9];
    const float* att3 = (const float*)d_in[10];
    const float* Wl4  = (const float*)d_in[11];
    const float* Wr4  = (const float*)d_in[12];
    const float* att4 = (const float*)d_in[13];

    const int N = in_sizes[0] / 128;
    const int E = in_sizes[1] / 2;
    const int* src = ei;
    const int* dst = ei + E;

    const int nb  = (N + 127) >> BSHIFT;
    const int nbp = (nb + 15) & ~15;
    const int NBd = (N + DCH - 1) / DCH;

    char* w = (char*)d_ws;
    size_t off = 0;
    auto take = [&](size_t bytes) -> void* {
        void* p = w + off;
        off = (off + bytes + 255) & ~(size_t)255;
        return p;
    };
    int* bcnt8    = (int*)take((size_t)8 * nbp * 4);
    int* bcur8    = (int*)take((size_t)8 * nbp * 4);
    int* bbase    = (int*)take((size_t)(nb + 1) * 4);
    int* rowstart = (int*)take((size_t)(N + 1) * 4);
    int* csr_src  = (int*)take((size_t)E * 4);
    int* bh       = (int*)take((size_t)256 * NBd * 4);
    int* perm     = (int*)take((size_t)N * 4);
    float* dl = (float*)take((size_t)N * 4);
    float* dr = (float*)take((size_t)N * 4);
    _Float16* xlh = (_Float16*)take((size_t)N * 64 * 2);
    _Float16* xrh = (_Float16*)take((size_t)N * 64 * 2);
    float* hA = (float*)take((size_t)N * 64 * 4);
    float* hB = (float*)take((size_t)N * 64 * 4);
    unsigned short* pWl1 = (unsigned short*)take(2 * 4 * 4 * 512 * 2);
    unsigned short* pWr1 = (unsigned short*)take(2 * 4 * 4 * 512 * 2);
    unsigned short* pWl2 = (unsigned short*)take(2 * 4 * 2 * 512 * 2);
    unsigned short* pWr2 = (unsigned short*)take(2 * 4 * 2 * 512 * 2);
    unsigned short* pWl3 = (unsigned short*)take(2 * 4 * 2 * 512 * 2);
    unsigned short* pWr3 = (unsigned short*)take(2 * 4 * 2 * 512 * 2);
    unsigned short* pWl4 = (unsigned short*)take(2 * 2 * 2 * 512 * 2);
    unsigned short* pWr4 = (unsigned short*)take(2 * 2 * 2 * 512 * 2);
    unsigned* pairs = (unsigned*)hA;   // aliases hA; consumed before layer-1 agg writes hA
    float* outf = (float*)d_out;

    hipMemsetAsync(bcnt8, 0, (size_t)8 * nbp * 4, stream);

    prepack_kernel<<<(2 * 4 * 4 * 512 + 255) / 256, 256, 0, stream>>>(Wl1, Wr1, pWl1, pWr1, 128, 64);
    prepack_kernel<<<(2 * 4 * 2 * 512 + 255) / 256, 256, 0, stream>>>(Wl2, Wr2, pWl2, pWr2, 64, 64);
    prepack_kernel<<<(2 * 4 * 2 * 512 + 255) / 256, 256, 0, stream>>>(Wl3, Wr3, pWl3, pWr3, 64, 64);
    prepack_kernel<<<(2 * 2 * 2 * 512 + 255) / 256, 256, 0, stream>>>(Wl4, Wr4, pWl4, pWr4, 64, 32);

    int kgrid = (E + CH - 1) / CH;
    bucket_hist<<<kgrid, 256, 0, stream>>>(dst, bcnt8, E, nb, nbp);
    bucket_scan<<<1, 1024, 0, stream>>>(bcnt8, bbase, bcur8, rowstart, nb, nbp, E, N);
    bucket_scatter<<<kgrid, 256, 0, stream>>>(src, dst, bcur8, pairs, E, nb, nbp);
    bucket_finalize<<<nb, 256, 0, stream>>>(pairs, bbase, rowstart, csr_src, N);

    // degree-sorted permutation (hierarchical counting sort, no global atomics)
    dsort_hist<<<NBd, 256, 0, stream>>>(rowstart, bh, N, NBd);
    dsort_scan<<<1, 256, 0, stream>>>(bh, NBd);
    dsort_scatter<<<NBd, 256, 0, stream>>>(rowstart, bh, perm, N, NBd);

    int pblk = (N + 63) / 64;
    int agg64 = (N + 31) / 32;    // 4 waves/block, 8 nodes/wave
    int agg32 = (N + 63) / 64;    // 4 waves/block, 16 nodes/wave

    // layer 1: 128 -> 64, ELU
    proj_mfma_kernel<128, 64><<<pblk, 256, 0, stream>>>(x, pWl1, pWr1, att1, xlh, xrh, dl, dr, N);
    agg_kernel<64, 1><<<agg64, 256, 0, stream>>>(xlh, xrh, att1, dl, dr, rowstart, csr_src, perm, hA, N, E);

    // layer 2: 64 -> 64, ELU
    proj_mfma_kernel<64, 64><<<pblk, 256, 0, stream>>>(hA, pWl2, pWr2, att2, xlh, xrh, dl, dr, N);
    agg_kernel<64, 1><<<agg64, 256, 0, stream>>>(xlh, xrh, att2, dl, dr, rowstart, csr_src, perm, hB, N, E);

    // layer 3: 64 -> 64, ELU
    proj_mfma_kernel<64, 64><<<pblk, 256, 0, stream>>>(hB, pWl3, pWr3, att3, xlh, xrh, dl, dr, N);
    agg_kernel<64, 1><<<agg64, 256, 0, stream>>>(xlh, xrh, att3, dl, dr, rowstart, csr_src, perm, hA, N, E);

    // layer 4: 64 -> 32, final ELU (alpha = 32)
    proj_mfma_kernel<64, 32><<<pblk, 256, 0, stream>>>(hA, pWl4, pWr4, att4, xlh, xrh, dl, dr, N);
    agg_kernel<32, 2><<<agg32, 256, 0, stream>>>(xlh, xrh, att4, dl, dr, rowstart, csr_src, perm, outf, N, E);
}

// Round 12
// 295.492 us; speedup vs baseline: 2.8605x; 1.1306x over previous
//
#include <hip/hip_runtime.h>
#include <math.h>

typedef __attribute__((ext_vector_type(8))) short bf16x8;
typedef __attribute__((ext_vector_type(4))) float f32x4;
typedef __attribute__((ext_vector_type(2))) _Float16 h2;

#define BSHIFT 7               // 128 nodes per bucket
#define CH 8192                // edges per block in bucket hist/scatter

__device__ inline unsigned short f32_to_bf16_bits(float f) {
    unsigned int u = __float_as_uint(f);
    unsigned int r = (u + 0x7fffu + ((u >> 16) & 1u)) >> 16;   // RNE
    return (unsigned short)r;
}
__device__ inline float bf16_bits_to_f32(unsigned short h) {
    return __uint_as_float(((unsigned int)h) << 16);
}
__device__ inline h2 u2h(unsigned u) { return __builtin_bit_cast(h2, u); }
__device__ inline unsigned h2u(h2 h) { return __builtin_bit_cast(unsigned, h); }

// single-instruction lane xor-swizzle add (BitMode: (xor<<10)|0x1F)
#define SWZ_ADD(t, imm) \
    t += __int_as_float(__builtin_amdgcn_ds_swizzle(__float_as_int(t), imm))

// fp16 pair dot with f32 accumulate (v_dot2_f32_f16)
__device__ inline float dot2acc(h2 a, h2 b, float c) {
#if defined(__has_builtin)
#if __has_builtin(__builtin_amdgcn_fdot2)
    return __builtin_amdgcn_fdot2(a, b, c, false);
#else
    return c + (float)a[0] * (float)b[0] + (float)a[1] * (float)b[1];
#endif
#else
    return c + (float)a[0] * (float)b[0] + (float)a[1] * (float)b[1];
#endif
}

// ================= 2-level bucket CSR build =================

__global__ __launch_bounds__(256) void bucket_hist(
    const int* __restrict__ dst, int* __restrict__ bcnt8, int E, int nb, int nbp)
{
    __shared__ int h[1024];
    for (int i = threadIdx.x; i < nb; i += 256) h[i] = 0;
    __syncthreads();
    int e0 = blockIdx.x * CH, e1 = min(e0 + CH, E);
    for (int e = e0 + (int)threadIdx.x; e < e1; e += 256)
        atomicAdd(&h[dst[e] >> BSHIFT], 1);
    __syncthreads();
    int* mycnt = bcnt8 + (blockIdx.x & 7) * nbp;
    for (int b = threadIdx.x; b < nb; b += 256) {
        int c = h[b];
        if (c) atomicAdd(&mycnt[b], c);
    }
}

__global__ void bucket_scan(const int* __restrict__ bcnt8, int* __restrict__ bbase,
                            int* __restrict__ bcur8, int* __restrict__ rowstart,
                            int nb, int nbp, int E, int N)
{
    __shared__ int sh[1024];
    int t = threadIdx.x;
    int g8[8];
    int tot = 0;
#pragma unroll
    for (int g = 0; g < 8; ++g) {
        int c = (t < nb) ? bcnt8[g * nbp + t] : 0;
        g8[g] = c; tot += c;
    }
    sh[t] = tot;
    __syncthreads();
    for (int d = 1; d < 1024; d <<= 1) {
        int a = (t >= d) ? sh[t - d] : 0;
        __syncthreads();
        sh[t] += a;
        __syncthreads();
    }
    int base = sh[t] - tot;   // exclusive
    if (t <= nb) bbase[t] = base;
    if (t < nb) {
        int run = base;
#pragma unroll
        for (int g = 0; g < 8; ++g) { bcur8[g * nbp + t] = run; run += g8[g]; }
    }
    if (t == 0) rowstart[N] = E;
}

__global__ __launch_bounds__(256) void bucket_scatter(
    const int* __restrict__ src, const int* __restrict__ dst,
    int* __restrict__ bcur8, unsigned* __restrict__ pairs, int E, int nb, int nbp)
{
    __shared__ int h[1024];
    for (int i = threadIdx.x; i < nb; i += 256) h[i] = 0;
    __syncthreads();
    int e0 = blockIdx.x * CH, e1 = min(e0 + CH, E);
    for (int e = e0 + (int)threadIdx.x; e < e1; e += 256)
        atomicAdd(&h[dst[e] >> BSHIFT], 1);
    __syncthreads();
    int* mycur = bcur8 + (blockIdx.x & 7) * nbp;
    for (int b = threadIdx.x; b < nb; b += 256) {
        int c = h[b];
        if (c) h[b] = atomicAdd(&mycur[b], c);
    }
    __syncthreads();
    for (int e = e0 + (int)threadIdx.x; e < e1; e += 256) {
        int d = dst[e];
        int pos = atomicAdd(&h[d >> BSHIFT], 1);
        pairs[pos] = ((unsigned)src[e] << BSHIFT) | (unsigned)(d & 127);
    }
}

__global__ __launch_bounds__(256) void bucket_finalize(
    const unsigned* __restrict__ pairs, const int* __restrict__ bbase,
    int* __restrict__ rowstart, int* __restrict__ csr_src, int N)
{
    __shared__ int h[128];
    __shared__ int sh[256];
    int b = blockIdx.x;
    int p0 = bbase[b], p1 = bbase[b + 1];
    int t = threadIdx.x;
    if (t < 128) h[t] = 0;
    __syncthreads();
    for (int e = p0 + t; e < p1; e += 256)
        atomicAdd(&h[pairs[e] & 127], 1);
    __syncthreads();
    int v = (t < 128) ? h[t] : 0;
    sh[t] = v;
    __syncthreads();
    for (int d = 1; d < 256; d <<= 1) {
        int a = (t >= d) ? sh[t - d] : 0;
        __syncthreads();
        sh[t] += a;
        __syncthreads();
    }
    if (t < 128) {
        int off = sh[t] - v;
        int node = (b << BSHIFT) + t;
        if (node < N) rowstart[node] = p0 + off;
        h[t] = p0 + off;
    }
    __syncthreads();
    for (int e = p0 + t; e < p1; e += 256) {
        unsigned pr = pairs[e];
        int pos = atomicAdd(&h[pr & 127], 1);
        csr_src[pos] = (int)(pr >> BSHIFT);
    }
}

// ================= weight prepack =================

__global__ void prepack_kernel(const float* __restrict__ Wl, const float* __restrict__ Wr,
                               unsigned short* __restrict__ pWl, unsigned short* __restrict__ pWr,
                               int FIN, int FOUT) {
    int NT = FOUT >> 4, NK = FIN >> 5;
    int part = NT * NK * 512;
    int i = blockIdx.x * blockDim.x + threadIdx.x;
    int m = i / part;
    if (m >= 2) return;
    int ii = i - m * part;
    int j = ii & 7;
    int lane = (ii >> 3) & 63;
    int rest = ii >> 9;
    int ks = rest % NK;
    int t = rest / NK;
    int k = ks * 32 + (lane >> 4) * 8 + j;
    int c = t * 16 + (lane & 15);
    const float* W = m ? Wr : Wl;
    unsigned short* P = m ? pWr : pWl;
    float w = W[(size_t)k * FOUT + c];
    unsigned short hi = f32_to_bf16_bits(w);
    unsigned short lo = f32_to_bf16_bits(w - bf16_bits_to_f32(hi));
    P[ii] = hi;
    P[part + ii] = lo;
}

// ================= MFMA projection + att-dot epilogue =================

template<int FIN, int FOUT>
__global__ __launch_bounds__(256) void proj_mfma_kernel(
    const float* __restrict__ x,
    const unsigned short* __restrict__ pWl, const unsigned short* __restrict__ pWr,
    const float* __restrict__ att,
    _Float16* __restrict__ xlh, _Float16* __restrict__ xrh,
    float* __restrict__ dl, float* __restrict__ dr, int n)
{
    constexpr int NT = FOUT >> 4;
    constexpr int NK = FIN >> 5;
    constexpr int PART = NT * NK * 512;
    const int wave = threadIdx.x >> 6;
    const int lane = threadIdx.x & 63;
    const int row0 = blockIdx.x * 64 + wave * 16;
    int arow = row0 + (lane & 15);
    if (arow >= n) arow = n - 1;
    const int khalf = lane >> 4;

    f32x4 accl[NT], accr[NT];
#pragma unroll
    for (int t = 0; t < NT; ++t) {
        accl[t] = (f32x4){0.f, 0.f, 0.f, 0.f};
        accr[t] = (f32x4){0.f, 0.f, 0.f, 0.f};
    }

    const float* xrow = x + (size_t)arow * FIN + khalf * 8;
#pragma unroll
    for (int ks = 0; ks < NK; ++ks) {
        float4 a0 = *(const float4*)(xrow + ks * 32);
        float4 a1 = *(const float4*)(xrow + ks * 32 + 4);
        float av[8] = {a0.x, a0.y, a0.z, a0.w, a1.x, a1.y, a1.z, a1.w};
        bf16x8 ah, al;
#pragma unroll
        for (int j = 0; j < 8; ++j) {
            unsigned short h = f32_to_bf16_bits(av[j]);
            ah[j] = (short)h;
            al[j] = (short)f32_to_bf16_bits(av[j] - bf16_bits_to_f32(h));
        }
#pragma unroll
        for (int t = 0; t < NT; ++t) {
            const unsigned short* bpl = pWl + ((size_t)(t * NK + ks) * 64 + lane) * 8;
            bf16x8 bh  = *(const bf16x8*)bpl;
            bf16x8 blo = *(const bf16x8*)(bpl + PART);
            accl[t] = __builtin_amdgcn_mfma_f32_16x16x32_bf16(ah, bh,  accl[t], 0, 0, 0);
            accl[t] = __builtin_amdgcn_mfma_f32_16x16x32_bf16(ah, blo, accl[t], 0, 0, 0);
            accl[t] = __builtin_amdgcn_mfma_f32_16x16x32_bf16(al, bh,  accl[t], 0, 0, 0);
            const unsigned short* bpr = pWr + ((size_t)(t * NK + ks) * 64 + lane) * 8;
            bh  = *(const bf16x8*)bpr;
            blo = *(const bf16x8*)(bpr + PART);
            accr[t] = __builtin_amdgcn_mfma_f32_16x16x32_bf16(ah, bh,  accr[t], 0, 0, 0);
            accr[t] = __builtin_amdgcn_mfma_f32_16x16x32_bf16(ah, blo, accr[t], 0, 0, 0);
            accr[t] = __builtin_amdgcn_mfma_f32_16x16x32_bf16(al, bh,  accr[t], 0, 0, 0);
        }
    }

    const int orow0 = row0 + khalf * 4;
    const int colb = lane & 15;
    float attc[NT];
#pragma unroll
    for (int t = 0; t < NT; ++t) attc[t] = att[t * 16 + colb];

#pragma unroll
    for (int t = 0; t < NT; ++t) {
        int col = t * 16 + colb;
#pragma unroll
        for (int r = 0; r < 4; ++r) {
            int rr = orow0 + r;
            if (rr < n) {
                xlh[(size_t)rr * FOUT + col] = (_Float16)accl[t][r];
                xrh[(size_t)rr * FOUT + col] = (_Float16)accr[t][r];
            }
        }
    }
#pragma unroll
    for (int r = 0; r < 4; ++r) {
        float pl = 0.f, pr = 0.f;
#pragma unroll
        for (int t = 0; t < NT; ++t) { pl += accl[t][r] * attc[t]; pr += accr[t][r] * attc[t]; }
#pragma unroll
        for (int off = 1; off < 16; off <<= 1) {
            pl += __shfl_xor(pl, off);
            pr += __shfl_xor(pr, off);
        }
        int rr = orow0 + r;
        if (colb == 0 && rr < n) { dl[rr] = pl; dr[rr] = pr; }
    }
}

// ================= per-dst online-softmax aggregation =================
// Group-per-node (natural order), 8 feats/lane packed-fp16 math.
// Staggered software pipeline with 2x-unrolled steady state:
//   csr indices consumed 1 full iteration after issue,
//   xl/dl data consumed 2 full iterations after issue,
//   no register-rotation moves (two buffer sets alternate).
// score = 0.6*(dl+dr) + 0.4*sum(att*|s|); pair-merged defer-max (thr 8).

template<int F, int AMODE>
__global__ __launch_bounds__(256) void agg_kernel(
    const _Float16* __restrict__ xlh, const _Float16* __restrict__ xrh,
    const float* __restrict__ att,
    const float* __restrict__ dl, const float* __restrict__ dr,
    const int* __restrict__ rowstart, const int* __restrict__ csr_src,
    float* __restrict__ out, int n, int E)
{
    constexpr int LPE = F / 8;            // lanes per node (8 feats/lane)
    constexpr int LSH = (F == 64) ? 6 : 5;
    constexpr int NPG = 64 / LPE;         // nodes per wave

    int wv  = (blockIdx.x * blockDim.x + threadIdx.x) >> 6;
    int lane = threadIdx.x & 63;
    int grp = lane / LPE;
    int fl  = lane % LPE;
    int node = wv * NPG + grp;
    bool act = node < n;
    int nc = act ? node : 0;

    float4 xrraw = *(const float4*)(xrh + (((unsigned)nc << LSH) + fl * 8));
    h2 xrv[4];
#pragma unroll
    for (int j = 0; j < 4; ++j) xrv[j] = u2h(((const unsigned*)&xrraw)[j]);
    h2 atth[4];
#pragma unroll
    for (int j = 0; j < 4; ++j) {
        atth[j][0] = (_Float16)att[fl * 8 + 2 * j];
        atth[j][1] = (_Float16)att[fl * 8 + 2 * j + 1];
    }
    float cdr = 0.6f * dr[nc];

    int s0 = rowstart[nc];
    int s1 = act ? rowstart[nc + 1] : s0;
    int s1c = min(max(s1 - 1, s0), E - 1);   // clamp inside own segment

    float m = -1e30f, mth = -1e30f, ssum = 0.f;
    float o[8];
#pragma unroll
    for (int j = 0; j < 8; ++j) o[j] = 0.f;

    // ---- prologue: pairs 0,1 data; pairs 2,3 csr indices ----
    int cA0 = csr_src[min(s0,     s1c)];
    int cB0 = csr_src[min(s0 + 1, s1c)];
    int cA1 = csr_src[min(s0 + 2, s1c)];
    int cB1 = csr_src[min(s0 + 3, s1c)];
    float4 rA0 = *(const float4*)(xlh + (((unsigned)cA0 << LSH) + fl * 8));
    float4 rB0 = *(const float4*)(xlh + (((unsigned)cB0 << LSH) + fl * 8));
    float  dA0 = dl[cA0], dB0 = dl[cB0];
    float4 rA1 = *(const float4*)(xlh + (((unsigned)cA1 << LSH) + fl * 8));
    float4 rB1 = *(const float4*)(xlh + (((unsigned)cB1 << LSH) + fl * 8));
    float  dA1 = dl[cA1], dB1 = dl[cB1];
    int fA0 = csr_src[min(s0 + 4, s1c)];   // pair 2 indices (cbuf0)
    int fB0 = csr_src[min(s0 + 5, s1c)];
    int fA1 = csr_src[min(s0 + 6, s1c)];   // pair 3 indices (cbuf1)
    int fB1 = csr_src[min(s0 + 7, s1c)];

    int i0 = s0;

#define AGG_COMPUTE(RA, RB, DA, DB)                                          \
    {                                                                        \
        h2 a[4], b[4];                                                       \
        _Pragma("unroll")                                                    \
        for (int j = 0; j < 4; ++j) {                                        \
            a[j] = u2h(((const unsigned*)&RA)[j]);                           \
            b[j] = u2h(((const unsigned*)&RB)[j]);                           \
        }                                                                    \
        bool vb = (i0 + 1) < s1;                                             \
        float ta = 0.f, tb = 0.f;                                            \
        _Pragma("unroll")                                                    \
        for (int j = 0; j < 4; ++j) {                                        \
            h2 ea = a[j] + xrv[j];                                           \
            h2 eb = b[j] + xrv[j];                                           \
            ea = u2h(h2u(ea) & 0x7FFF7FFFu);                                 \
            eb = u2h(h2u(eb) & 0x7FFF7FFFu);                                 \
            ta = dot2acc(atth[j], ea, ta);                                   \
            tb = dot2acc(atth[j], eb, tb);                                   \
        }                                                                    \
        SWZ_ADD(ta, 0x041F); SWZ_ADD(tb, 0x041F);                            \
        SWZ_ADD(ta, 0x081F); SWZ_ADD(tb, 0x081F);                            \
        if (LPE == 8) { SWZ_ADD(ta, 0x101F); SWZ_ADD(tb, 0x101F); }          \
        float pa = 0.6f * DA + cdr + 0.4f * ta;                              \
        float pb = vb ? (0.6f * DB + cdr + 0.4f * tb) : -1e30f;              \
        float pm = fmaxf(pa, pb);                                            \
        if (pm > mth) {                                                      \
            float c = __expf(m - pm);                                        \
            ssum *= c;                                                       \
            _Pragma("unroll")                                                \
            for (int j = 0; j < 8; ++j) o[j] *= c;                           \
            m = pm; mth = pm + 8.0f;                                         \
        }                                                                    \
        float wa = __expf(pa - m);                                           \
        float wb = __expf(pb - m);                                           \
        ssum += wa + wb;                                                     \
        _Pragma("unroll")                                                    \
        for (int j = 0; j < 4; ++j) {                                        \
            o[2 * j]     += wa * (float)a[j][0] + wb * (float)b[j][0];       \
            o[2 * j + 1] += wa * (float)a[j][1] + wb * (float)b[j][1];       \
        }                                                                    \
    }

    while (i0 < s1) {
        // ---- step 0: consume buf0 (pair i0), cbuf0 (pair i0+2) ----
        {
            int cA2 = fA0, cB2 = fB0;                      // 1-iter-old csr values
            fA0 = csr_src[min(i0 + 8, s1c)];               // csr for pair i0+4
            fB0 = csr_src[min(i0 + 9, s1c)];
            AGG_COMPUTE(rA0, rB0, dA0, dB0);               // waits on 2-iter-old data
            rA0 = *(const float4*)(xlh + (((unsigned)cA2 << LSH) + fl * 8));  // data for pair i0+2
            rB0 = *(const float4*)(xlh + (((unsigned)cB2 << LSH) + fl * 8));
            dA0 = dl[cA2]; dB0 = dl[cB2];
        }
        i0 += 2;
        if (i0 >= s1) break;
        // ---- step 1: consume buf1 (pair i0), cbuf1 (pair i0+2) ----
        {
            int cA2 = fA1, cB2 = fB1;
            fA1 = csr_src[min(i0 + 8, s1c)];
            fB1 = csr_src[min(i0 + 9, s1c)];
            AGG_COMPUTE(rA1, rB1, dA1, dB1);
            rA1 = *(const float4*)(xlh + (((unsigned)cA2 << LSH) + fl * 8));
            rB1 = *(const float4*)(xlh + (((unsigned)cB2 << LSH) + fl * 8));
            dA1 = dl[cA2]; dB1 = dl[cB2];
        }
        i0 += 2;
    }
#undef AGG_COMPUTE

    float inv = 1.f / (ssum + 1e-16f);
    float res[8];
#pragma unroll
    for (int j = 0; j < 8; ++j) {
        float r = o[j] * inv;
        if (AMODE == 1) r = (r > 0.f) ? r : expm1f(r);
        else            r = (r > 0.f) ? r : 32.f * expm1f(r);
        res[j] = r;
    }
    if (act) {
        float* op = out + (((unsigned)node << LSH) + fl * 8);
        *(float4*)op       = (float4){res[0], res[1], res[2], res[3]};
        *(float4*)(op + 4) = (float4){res[4], res[5], res[6], res[7]};
    }
}

// ================= launcher =================

extern "C" void kernel_launch(void* const* d_in, const int* in_sizes, int n_in,
                              void* d_out, int out_size, void* d_ws, size_t ws_size,
                              hipStream_t stream) {
    const float* x    = (const float*)d_in[0];
    const int*   ei   = (const int*)d_in[1];
    const float* Wl1  = (const float*)d_in[2];
    const float* Wr1  = (const float*)d_in[3];
    const float* att1 = (const float*)d_in[4];
    const float* Wl2  = (const float*)d_in[5];
    const float* Wr2  = (const float*)d_in[6];
    const float* att2 = (const float*)d_in[7];
    const float* Wl3  = (const float*)d_in[8];
    const float* Wr3  = (const float*)d_in[9];
    const float* att3 = (const float*)d_in[10];
    const float* Wl4  = (const float*)d_in[11];
    const float* Wr4  = (const float*)d_in[12];
    const float* att4 = (const float*)d_in[13];

    const int N = in_sizes[0] / 128;
    const int E = in_sizes[1] / 2;
    const int* src = ei;
    const int* dst = ei + E;

    const int nb  = (N + 127) >> BSHIFT;
    const int nbp = (nb + 15) & ~15;

    char* w = (char*)d_ws;
    size_t off = 0;
    auto take = [&](size_t bytes) -> void* {
        void* p = w + off;
        off = (off + bytes + 255) & ~(size_t)255;
        return p;
    };
    int* bcnt8    = (int*)take((size_t)8 * nbp * 4);
    int* bcur8    = (int*)take((size_t)8 * nbp * 4);
    int* bbase    = (int*)take((size_t)(nb + 1) * 4);
    int* rowstart = (int*)take((size_t)(N + 1) * 4);
    int* csr_src  = (int*)take((size_t)E * 4);
    float* dl = (float*)take((size_t)N * 4);
    float* dr = (float*)take((size_t)N * 4);
    _Float16* xlh = (_Float16*)take((size_t)N * 64 * 2);
    _Float16* xrh = (_Float16*)take((size_t)N * 64 * 2);
    float* hA = (float*)take((size_t)N * 64 * 4);
    float* hB = (float*)take((size_t)N * 64 * 4);
    unsigned short* pWl1 = (unsigned short*)take(2 * 4 * 4 * 512 * 2);
    unsigned short* pWr1 = (unsigned short*)take(2 * 4 * 4 * 512 * 2);
    unsigned short* pWl2 = (unsigned short*)take(2 * 4 * 2 * 512 * 2);
    unsigned short* pWr2 = (unsigned short*)take(2 * 4 * 2 * 512 * 2);
    unsigned short* pWl3 = (unsigned short*)take(2 * 4 * 2 * 512 * 2);
    unsigned short* pWr3 = (unsigned short*)take(2 * 4 * 2 * 512 * 2);
    unsigned short* pWl4 = (unsigned short*)take(2 * 2 * 2 * 512 * 2);
    unsigned short* pWr4 = (unsigned short*)take(2 * 2 * 2 * 512 * 2);
    unsigned* pairs = (unsigned*)hA;   // aliases hA; consumed before layer-1 agg writes hA
    float* outf = (float*)d_out;

    hipMemsetAsync(bcnt8, 0, (size_t)8 * nbp * 4, stream);

    prepack_kernel<<<(2 * 4 * 4 * 512 + 255) / 256, 256, 0, stream>>>(Wl1, Wr1, pWl1, pWr1, 128, 64);
    prepack_kernel<<<(2 * 4 * 2 * 512 + 255) / 256, 256, 0, stream>>>(Wl2, Wr2, pWl2, pWr2, 64, 64);
    prepack_kernel<<<(2 * 4 * 2 * 512 + 255) / 256, 256, 0, stream>>>(Wl3, Wr3, pWl3, pWr3, 64, 64);
    prepack_kernel<<<(2 * 2 * 2 * 512 + 255) / 256, 256, 0, stream>>>(Wl4, Wr4, pWl4, pWr4, 64, 32);

    int kgrid = (E + CH - 1) / CH;
    bucket_hist<<<kgrid, 256, 0, stream>>>(dst, bcnt8, E, nb, nbp);
    bucket_scan<<<1, 1024, 0, stream>>>(bcnt8, bbase, bcur8, rowstart, nb, nbp, E, N);
    bucket_scatter<<<kgrid, 256, 0, stream>>>(src, dst, bcur8, pairs, E, nb, nbp);
    bucket_finalize<<<nb, 256, 0, stream>>>(pairs, bbase, rowstart, csr_src, N);

    int pblk = (N + 63) / 64;
    int agg64 = (N + 31) / 32;    // 4 waves/block, 8 nodes/wave
    int agg32 = (N + 63) / 64;    // 4 waves/block, 16 nodes/wave

    // layer 1: 128 -> 64, ELU
    proj_mfma_kernel<128, 64><<<pblk, 256, 0, stream>>>(x, pWl1, pWr1, att1, xlh, xrh, dl, dr, N);
    agg_kernel<64, 1><<<agg64, 256, 0, stream>>>(xlh, xrh, att1, dl, dr, rowstart, csr_src, hA, N, E);

    // layer 2: 64 -> 64, ELU
    proj_mfma_kernel<64, 64><<<pblk, 256, 0, stream>>>(hA, pWl2, pWr2, att2, xlh, xrh, dl, dr, N);
    agg_kernel<64, 1><<<agg64, 256, 0, stream>>>(xlh, xrh, att2, dl, dr, rowstart, csr_src, hB, N, E);

    // layer 3: 64 -> 64, ELU
    proj_mfma_kernel<64, 64><<<pblk, 256, 0, stream>>>(hB, pWl3, pWr3, att3, xlh, xrh, dl, dr, N);
    agg_kernel<64, 1><<<agg64, 256, 0, stream>>>(xlh, xrh, att3, dl, dr, rowstart, csr_src, hA, N, E);

    // layer 4: 64 -> 32, final ELU (alpha = 32)
    proj_mfma_kernel<64, 32><<<pblk, 256, 0, stream>>>(hA, pWl4, pWr4, att4, xlh, xrh, dl, dr, N);
    agg_kernel<32, 2><<<agg32, 256, 0, stream>>>(xlh, xrh, att4, dl, dr, rowstart, csr_src, outf, N, E);
}